// Round 14
// baseline (443.899 us; speedup 1.0000x reference)
//
#include <hip/hip_runtime.h>
#include <hip/hip_fp16.h>
#include <stddef.h>

static constexpr int Nn    = 100000;
static constexpr int Ee    = 1600000;
static constexpr int Ff    = 128;
static constexpr int Cc    = 64;
static constexpr int NHh   = 256;
static constexpr int NOUTt = 128;
static constexpr int Ll    = 4;
static constexpr int Gg    = 512;

static constexpr int SCAN_BLK = 1024;
static constexpr int NBLK_SCAN = (Nn + SCAN_BLK - 1) / SCAN_BLK;   // 98

static constexpr int NSUB   = (Nn + 511) / 512;   // 196
static constexpr int SUBCAP = 10240;

typedef _Float16 half8 __attribute__((ext_vector_type(8)));
typedef float    f32x4 __attribute__((ext_vector_type(4)));

// ---------------- pass 1: bin edges by dst>>9 into 196 sub-buckets ----------------
__global__ __launch_bounds__(256) void bin_kernel(const int* __restrict__ src,
                                                  const int* __restrict__ dst,
                                                  int* __restrict__ sb,
                                                  int* __restrict__ scnt, int E) {
    __shared__ int lcnt[NSUB], lbase[NSUB];
    const int tid = threadIdx.x;
    for (int i = tid; i < NSUB; i += 256) lcnt[i] = 0;
    __syncthreads();
    const int base = blockIdx.x * 2048;
    int pk[8], ps[8], lr[8];
    #pragma unroll
    for (int i = 0; i < 8; ++i) {
        int e = base + i * 256 + tid;
        if (e < E) {
            int d = dst[e], s = src[e];
            int sub = d >> 9;
            ps[i] = sub;
            pk[i] = s | ((d & 511) << 17);
            lr[i] = atomicAdd(&lcnt[sub], 1);
        } else ps[i] = -1;
    }
    __syncthreads();
    for (int i = tid; i < NSUB; i += 256) lbase[i] = atomicAdd(&scnt[i], lcnt[i]);
    __syncthreads();
    #pragma unroll
    for (int i = 0; i < 8; ++i) {
        if (ps[i] >= 0) {
            int pos = lbase[ps[i]] + lr[i];
            if (pos < SUBCAP) sb[(size_t)ps[i] * SUBCAP + pos] = pk[i];
        }
    }
}

// ---------------- pass 2a: degree + dinv ----------------
__global__ __launch_bounds__(512) void cnt3_kernel(const int* __restrict__ sb,
                                                   const int* __restrict__ scnt,
                                                   int* __restrict__ cnt,
                                                   float* __restrict__ dinv) {
    __shared__ int lcnt[512];
    const int sub = blockIdx.x, tid = threadIdx.x;
    lcnt[tid] = 0;
    __syncthreads();
    const int n = scnt[sub];
    const int* bp = sb + (size_t)sub * SUBCAP;
    for (int i = tid; i < n; i += 512) atomicAdd(&lcnt[(bp[i] >> 17) & 511], 1);
    __syncthreads();
    int node = sub * 512 + tid;
    if (node < Nn) {
        cnt[node] = lcnt[tid];
        dinv[node] = rsqrtf((float)lcnt[tid] + 1.0f);
    }
}

// ---------------- scans ----------------
__global__ __launch_bounds__(SCAN_BLK) void scan1_kernel(const int* __restrict__ cnt,
                                                         int* __restrict__ row_off,
                                                         int* __restrict__ bsum, int n) {
    __shared__ int sd[SCAN_BLK];
    int tid = threadIdx.x;
    int gid = blockIdx.x * SCAN_BLK + tid;
    int v = (gid < n) ? cnt[gid] : 0;
    sd[tid] = v;
    __syncthreads();
    #pragma unroll
    for (int off = 1; off < SCAN_BLK; off <<= 1) {
        int t = (tid >= off) ? sd[tid - off] : 0;
        __syncthreads();
        sd[tid] += t;
        __syncthreads();
    }
    if (gid < n) row_off[gid + 1] = sd[tid];
    if (tid == SCAN_BLK - 1) bsum[blockIdx.x] = sd[tid];
}

__global__ __launch_bounds__(128) void scan2_kernel(const int* __restrict__ bsum,
                                                    int* __restrict__ boff, int nb) {
    __shared__ int sd[128];
    int tid = threadIdx.x;
    sd[tid] = (tid < nb) ? bsum[tid] : 0;
    __syncthreads();
    #pragma unroll
    for (int off = 1; off < 128; off <<= 1) {
        int t = (tid >= off) ? sd[tid - off] : 0;
        __syncthreads();
        sd[tid] += t;
        __syncthreads();
    }
    if (tid < nb) boff[tid] = (tid == 0) ? 0 : sd[tid - 1];
}

__global__ void scan3_kernel(int* __restrict__ row_off, const int* __restrict__ boff,
                             const int* __restrict__ batch, int* __restrict__ gstart, int n) {
    int gid = blockIdx.x * blockDim.x + threadIdx.x;
    if (gid < n) {
        row_off[gid + 1] += boff[gid >> 10];
        int bi = batch[gid];
        int bp = (gid == 0) ? -1 : batch[gid - 1];
        for (int g = bp + 1; g <= bi; ++g) gstart[g] = gid;
        if (gid == n - 1) {
            for (int g = bi + 1; g <= Gg; ++g) gstart[g] = n;
        }
    }
    if (gid == 0) row_off[0] = 0;
}

// ---------------- pass 2b: fill csr ----------------
__global__ __launch_bounds__(512) void fill3_kernel(const int* __restrict__ sb,
                                                    const int* __restrict__ scnt,
                                                    const int* __restrict__ roff,
                                                    int* __restrict__ csr) {
    __shared__ int lcnt[512], lofs[512];
    __shared__ int gbase;
    const int sub = blockIdx.x, tid = threadIdx.x;
    lcnt[tid] = 0;
    if (tid == 0) gbase = roff[sub * 512];
    __syncthreads();
    const int n = scnt[sub];
    const int* bp = sb + (size_t)sub * SUBCAP;
    for (int i = tid; i < n; i += 512) atomicAdd(&lcnt[(bp[i] >> 17) & 511], 1);
    __syncthreads();
    int v = lcnt[tid];
    lofs[tid] = v;
    __syncthreads();
    #pragma unroll
    for (int off = 1; off < 512; off <<= 1) {
        int t = (tid >= off) ? lofs[tid - off] : 0;
        __syncthreads();
        lofs[tid] += t;
        __syncthreads();
    }
    int excl = lofs[tid] - v;
    __syncthreads();
    lcnt[tid] = excl;
    __syncthreads();
    for (int i = tid; i < n; i += 512) {
        int e = bp[i];
        int pos = atomicAdd(&lcnt[(e >> 17) & 511], 1);
        csr[gbase + pos] = e & 0x1FFFF;
    }
}

// ---------------- W pre-convert: W0 (128x64) + Wh (4x64x64) -> fragment-ordered fp16 ----
// W0 frags f=0..15 (ct=f>>2, c=f&3):  Wf[(f*64+lane)*8+j] = W0[c*32+(lane>>4)*8+j][ct*16+(lane&15)]
// Wh frags f=0..7  (ct=f>>1, c=f&1):  Wf[8192 + L*4096 + (f*64+lane)*8+j] = Wh[L][c*32+(lane>>4)*8+j][ct*16+(lane&15)]
__global__ __launch_bounds__(512) void wcvt_kernel(const float* __restrict__ W0,
                                                   const float* __restrict__ Wh,
                                                   _Float16* __restrict__ Wf) {
    int t = blockIdx.x * blockDim.x + threadIdx.x;
    if (t < 1024) {
        int f = t >> 6, lane = t & 63;
        int ct = f >> 2, c = f & 3;
        _Float16* o = Wf + ((size_t)f * 64 + lane) * 8;
        int kbase = c * 32 + (lane >> 4) * 8;
        int col = ct * 16 + (lane & 15);
        #pragma unroll
        for (int j = 0; j < 8; ++j) o[j] = (_Float16)W0[(size_t)(kbase + j) * 64 + col];
    } else if (t < 1024 + 2048) {
        int u = t - 1024;
        int layer = u >> 9, rem = u & 511;
        int f = rem >> 6, lane = rem & 63;
        int ct = f >> 1, c = f & 1;
        _Float16* o = Wf + 8192 + (size_t)layer * 4096 + ((size_t)f * 64 + lane) * 8;
        int kbase = c * 32 + (lane >> 4) * 8;
        int col = ct * 16 + (lane & 15);
        #pragma unroll
        for (int j = 0; j < 8; ++j)
            o[j] = (_Float16)Wh[(size_t)layer * 4096 + (size_t)(kbase + j) * 64 + col];
    }
}

// ---------------- layer-0 GEMM via MFMA (K=128, in-register fp32->fp16) ----------------
__global__ __launch_bounds__(256) void gemm0_mfma(const float* __restrict__ X,
                                                  const _Float16* __restrict__ Wf0,
                                                  const float* __restrict__ dinv,
                                                  __half* __restrict__ Y, int n) {
    __shared__ _Float16 lds[4][16 * 72];
    const int tid = threadIdx.x, lane = tid & 63, w = tid >> 6;
    const int wid = (blockIdx.x * 256 + tid) >> 6;
    if (wid >= (n >> 4)) return;
    const int node0 = wid * 16;

    half8 bf[16];
    #pragma unroll
    for (int f = 0; f < 16; ++f)
        bf[f] = *(const half8*)(Wf0 + ((size_t)f * 64 + lane) * 8);

    const float* xp = X + (size_t)(node0 + (lane & 15)) * Ff + (lane >> 4) * 8;
    f32x4 acc[4] = {};
    #pragma unroll
    for (int c = 0; c < 4; ++c) {
        float4 x0 = *(const float4*)(xp + c * 32);
        float4 x1 = *(const float4*)(xp + c * 32 + 4);
        half8 af;
        af[0] = (_Float16)x0.x; af[1] = (_Float16)x0.y; af[2] = (_Float16)x0.z; af[3] = (_Float16)x0.w;
        af[4] = (_Float16)x1.x; af[5] = (_Float16)x1.y; af[6] = (_Float16)x1.z; af[7] = (_Float16)x1.w;
        #pragma unroll
        for (int ct = 0; ct < 4; ++ct)
            acc[ct] = __builtin_amdgcn_mfma_f32_16x16x32_f16(af, bf[ct * 4 + c], acc[ct], 0, 0, 0);
    }

    const int r0 = (lane >> 4) * 4;
    float di[4];
    #pragma unroll
    for (int r = 0; r < 4; ++r) di[r] = dinv[node0 + r0 + r];
    #pragma unroll
    for (int ct = 0; ct < 4; ++ct)
        #pragma unroll
        for (int r = 0; r < 4; ++r)
            lds[w][(r0 + r) * 72 + ct * 16 + (lane & 15)] = (_Float16)(acc[ct][r] * di[r]);
    asm volatile("s_waitcnt lgkmcnt(0)" ::: "memory");
    #pragma unroll
    for (int p = 0; p < 2; ++p) {
        int row = p * 8 + (lane >> 3);
        int ch  = lane & 7;
        half8 v = *(const half8*)&lds[w][row * 72 + ch * 8];
        *(half8*)((_Float16*)Y + (size_t)(node0 + row) * 64 + ch * 8) = v;
    }
}

// ---------------- fp16 helpers ----------------
__device__ inline void add_h8(float acc[8], float4 raw) {
    const __half2* hp = reinterpret_cast<const __half2*>(&raw);
    #pragma unroll
    for (int j = 0; j < 4; ++j) {
        float2 f = __half22float2(hp[j]);
        acc[2 * j]     += f.x;
        acc[2 * j + 1] += f.y;
    }
}

__device__ inline void cvt_h8(float4 raw, float v[8]) {
    const __half2* hp = reinterpret_cast<const __half2*>(&raw);
    #pragma unroll
    for (int j = 0; j < 4; ++j) {
        float2 f = __half22float2(hp[j]);
        v[2 * j] = f.x; v[2 * j + 1] = f.y;
    }
}

// ---------------- fused gather(+relu+bias) -> [MFMA gemm] ----------------
// One wave per 16-node tile. Per node: CSR gather of t' rows (8 edge-slots,
// butterfly reduce), h = relu(di*(acc+self)+b) parked in per-wave LDS slab
// (stride 72 -> bank-safe). If GEMM: MFMA 16x64 h-tile against frag-ordered W,
// t'_next = di*(h@W) stored. Else: store h. Wave-local LDS only, no barriers.
template<bool GEMM>
__global__ __launch_bounds__(256) void gather_fused(const int* __restrict__ row_off,
                                                    const int* __restrict__ csr_src,
                                                    const float* __restrict__ dinv,
                                                    const __half* __restrict__ Tin,
                                                    const float* __restrict__ b,
                                                    const _Float16* __restrict__ Wf,
                                                    __half* __restrict__ out, int n) {
    __shared__ _Float16 hl[4][16 * 72];
    const int tid = threadIdx.x, lane = tid & 63, w = tid >> 6;
    const int wid = (blockIdx.x * 256 + tid) >> 6;
    if (wid >= (n >> 4)) return;
    const int node0 = wid * 16;
    const int sub = lane >> 3;
    const int c8  = lane & 7;

    half8 bfrag[8];
    if (GEMM) {
        #pragma unroll
        for (int f = 0; f < 8; ++f)
            bfrag[f] = *(const half8*)(Wf + ((size_t)f * 64 + lane) * 8);
    }

    // bias for my 8 channels (same for all 16 nodes)
    float4 bb0 = *(const float4*)(b + c8 * 8);
    float4 bb1 = *(const float4*)(b + c8 * 8 + 4);
    float bbv[8] = {bb0.x, bb0.y, bb0.z, bb0.w, bb1.x, bb1.y, bb1.z, bb1.w};

    for (int i = 0; i < 16; ++i) {
        const int node = node0 + i;
        const int base = row_off[node];
        const int end  = row_off[node + 1];

        float acc[8] = {};
        for (int k0 = base; k0 < end; k0 += 64) {
            int myidx = (k0 + lane < end) ? csr_src[k0 + lane] : 0;
            int nk = min(64, end - k0);
            int k = 0;
            for (; k + 16 <= nk; k += 16) {
                int s0 = __shfl(myidx, k + sub);
                int s1 = __shfl(myidx, k + 8 + sub);
                float4 r0 = *(const float4*)(Tin + (size_t)s0 * 64 + c8 * 8);
                float4 r1 = *(const float4*)(Tin + (size_t)s1 * 64 + c8 * 8);
                add_h8(acc, r0);
                add_h8(acc, r1);
            }
            for (; k < nk; k += 8) {
                int kk = k + sub;
                int s = __shfl(myidx, kk);
                if (kk < nk) {
                    float4 r = *(const float4*)(Tin + (size_t)s * 64 + c8 * 8);
                    add_h8(acc, r);
                }
            }
        }

        #pragma unroll
        for (int off = 8; off < 64; off <<= 1) {
            #pragma unroll
            for (int j = 0; j < 8; ++j) acc[j] += __shfl_xor(acc[j], off);
        }

        if (sub == 0) {
            float di = dinv[node];
            float selfv[8];
            cvt_h8(*(const float4*)(Tin + (size_t)node * 64 + c8 * 8), selfv);
            _Float16 hv[8];
            #pragma unroll
            for (int j = 0; j < 8; ++j)
                hv[j] = (_Float16)fmaxf(di * (acc[j] + selfv[j]) + bbv[j], 0.f);
            if (GEMM) {
                *(half8*)&hl[w][i * 72 + c8 * 8] = *(const half8*)hv;
            } else {
                *(half8*)((_Float16*)out + (size_t)node * 64 + c8 * 8) = *(const half8*)hv;
            }
        }
    }

    if (GEMM) {
        asm volatile("s_waitcnt lgkmcnt(0)" ::: "memory");
        // A-frags from LDS: lane holds H[node0+(l&15)][(l>>4)*8 + {0..7, 32..39}]
        const int row = lane & 15, q = lane >> 4;
        half8 a0 = *(const half8*)&hl[w][row * 72 + q * 8];
        half8 a1 = *(const half8*)&hl[w][row * 72 + 32 + q * 8];
        f32x4 acc2[4] = {};
        #pragma unroll
        for (int ct = 0; ct < 4; ++ct) {
            acc2[ct] = __builtin_amdgcn_mfma_f32_16x16x32_f16(a0, bfrag[ct * 2 + 0], acc2[ct], 0, 0, 0);
            acc2[ct] = __builtin_amdgcn_mfma_f32_16x16x32_f16(a1, bfrag[ct * 2 + 1], acc2[ct], 0, 0, 0);
        }
        asm volatile("s_waitcnt lgkmcnt(0)" ::: "memory");   // a0/a1 in regs before slab reuse
        const int r0 = q * 4;
        float di[4];
        #pragma unroll
        for (int r = 0; r < 4; ++r) di[r] = dinv[node0 + r0 + r];
        #pragma unroll
        for (int ct = 0; ct < 4; ++ct)
            #pragma unroll
            for (int r = 0; r < 4; ++r)
                hl[w][(r0 + r) * 72 + ct * 16 + (lane & 15)] = (_Float16)(acc2[ct][r] * di[r]);
        asm volatile("s_waitcnt lgkmcnt(0)" ::: "memory");
        #pragma unroll
        for (int p = 0; p < 2; ++p) {
            int orow = p * 8 + (lane >> 3);
            int ch   = lane & 7;
            half8 v = *(const half8*)&hl[w][orow * 72 + ch * 8];
            *(half8*)((_Float16*)out + (size_t)(node0 + orow) * 64 + ch * 8) = v;
        }
    }
}

// ---------------- pooling via sorted-batch segments ----------------
__global__ __launch_bounds__(256) void pool_graph(const __half* __restrict__ h,
                                                  const int* __restrict__ gstart,
                                                  float* __restrict__ pooled) {
    __shared__ float sd[4][64];
    const int g    = blockIdx.x;
    const int lane = threadIdx.x & 63;
    const int wv   = threadIdx.x >> 6;
    const int s = gstart[g], e = gstart[g + 1];
    float acc = 0.f;
    for (int i = s + wv; i < e; i += 4) acc += __half2float(h[(size_t)i * 64 + lane]);
    sd[wv][lane] = acc;
    __syncthreads();
    if (wv == 0) {
        float sum = sd[0][lane] + sd[1][lane] + sd[2][lane] + sd[3][lane];
        float c = (float)(e - s);
        pooled[(size_t)g * 64 + lane] = sum / fmaxf(c, 1.f);
    }
}

// ---------------- MLP head ----------------
__global__ void mlp1_kernel(const float* __restrict__ P, const float* __restrict__ W1,
                            const float* __restrict__ b1, float* __restrict__ H) {
    int gid = blockIdx.x * blockDim.x + threadIdx.x;
    if (gid >= Gg * NHh) return;
    int j = gid & (NHh - 1), g = gid >> 8;
    const float* p = P + (size_t)g * Cc;
    float s = b1[j];
    #pragma unroll 8
    for (int k = 0; k < Cc; ++k) s += p[k] * W1[(size_t)k * NHh + j];
    H[gid] = fmaxf(s, 0.f);
}

__global__ void mlp2_kernel(const float* __restrict__ H, const float* __restrict__ W2,
                            const float* __restrict__ b2, float* __restrict__ O) {
    int gid = blockIdx.x * blockDim.x + threadIdx.x;
    if (gid >= Gg * NOUTt) return;
    int j = gid & (NOUTt - 1), g = gid >> 7;
    const float* h = H + (size_t)g * NHh;
    float s = b2[j];
    #pragma unroll 8
    for (int k = 0; k < NHh; ++k) s += h[k] * W2[(size_t)k * NOUTt + j];
    O[gid] = s;
}

// ---------------- launch ----------------
extern "C" void kernel_launch(void* const* d_in, const int* in_sizes, int n_in,
                              void* d_out, int out_size, void* d_ws, size_t ws_size,
                              hipStream_t stream) {
    const float* x     = (const float*)d_in[0];
    const int*   ei    = (const int*)  d_in[1];
    const int*   batch = (const int*)  d_in[2];
    const float* W0    = (const float*)d_in[3];
    const float* b0    = (const float*)d_in[4];
    const float* Wh    = (const float*)d_in[5];
    const float* bh    = (const float*)d_in[6];
    const float* W1    = (const float*)d_in[7];
    const float* b1    = (const float*)d_in[8];
    const float* W2    = (const float*)d_in[9];
    const float* b2    = (const float*)d_in[10];

    const int* src = ei;
    const int* dst = ei + Ee;

    char* ws = (char*)d_ws;
    constexpr size_t OFF_DINV  = 0;
    constexpr size_t OFF_CNT   = 400384;
    constexpr size_t OFF_ROFF  = OFF_CNT + 400384;
    constexpr size_t OFF_BSUM  = OFF_ROFF + 400384;
    constexpr size_t OFF_BOFF  = OFF_BSUM + 1024;
    constexpr size_t OFF_SCNT  = OFF_BOFF + 1024;
    constexpr size_t OFF_CSR   = OFF_SCNT + 1024;
    constexpr size_t OFF_T     = OFF_CSR + 6400256;       // fp16 12.8MB
    constexpr size_t OFF_T2    = OFF_T + 12800256;        // fp16 12.8MB
    constexpr size_t OFF_A     = OFF_T2 + 12800256;       // fp16 h 12.8MB
    constexpr size_t OFF_POOL  = OFF_A + 12800256;
    constexpr size_t OFF_GST   = OFF_POOL + (size_t)Gg * Cc * 4;
    constexpr size_t OFF_HID   = OFF_GST + 4096;
    constexpr size_t OFF_WF    = OFF_HID + (size_t)Gg * NHh * 4;  // 48KB frag W0+Wh
    const size_t OFF_SB = OFF_T;   // sub-buckets (8.03MB) alias T (dead until gemm0)

    float*    dinv   = (float*)   (ws + OFF_DINV);
    int*      cnt    = (int*)     (ws + OFF_CNT);
    int*      roff   = (int*)     (ws + OFF_ROFF);
    int*      bsum   = (int*)     (ws + OFF_BSUM);
    int*      boff   = (int*)     (ws + OFF_BOFF);
    int*      scnt   = (int*)     (ws + OFF_SCNT);
    int*      csrs   = (int*)     (ws + OFF_CSR);
    int*      sb     = (int*)     (ws + OFF_SB);
    __half*   T      = (__half*)  (ws + OFF_T);
    __half*   T2     = (__half*)  (ws + OFF_T2);
    __half*   A      = (__half*)  (ws + OFF_A);
    float*    pooled = (float*)   (ws + OFF_POOL);
    int*      gstart = (int*)     (ws + OFF_GST);
    float*    hid    = (float*)   (ws + OFF_HID);
    _Float16* Wf     = (_Float16*)(ws + OFF_WF);
    _Float16* Wfh    = Wf + 8192;   // hidden-layer frags

    // ---- CSR build + W pre-convert ----
    hipMemsetAsync(scnt, 0, 1024, stream);
    wcvt_kernel<<<6, 512, 0, stream>>>(W0, Wh, Wf);
    bin_kernel<<<(Ee + 2047) / 2048, 256, 0, stream>>>(src, dst, sb, scnt, Ee);
    cnt3_kernel<<<NSUB, 512, 0, stream>>>(sb, scnt, cnt, dinv);
    scan1_kernel<<<NBLK_SCAN, SCAN_BLK, 0, stream>>>(cnt, roff, bsum, Nn);
    scan2_kernel<<<1, 128, 0, stream>>>(bsum, boff, NBLK_SCAN);
    scan3_kernel<<<(Nn + 255) / 256, 256, 0, stream>>>(roff, boff, batch, gstart, Nn);
    fill3_kernel<<<NSUB, 512, 0, stream>>>(sb, scnt, roff, csrs);

    const int tile_blocks = ((Nn / 16) + 3) / 4;   // 1563: 4 waves/block, 16 nodes/wave

    // ---- layer 0 GEMM: T = fp16(dinv * (x @ W0)) via MFMA K=128 ----
    gemm0_mfma<<<tile_blocks, 256, 0, stream>>>(x, Wf, dinv, T, Nn);

    // ---- 5 fused gather(+next GEMM) steps ----
    gather_fused<true ><<<tile_blocks, 256, 0, stream>>>(roff, csrs, dinv, T,  b0,       Wfh + 0 * 4096, T2, Nn);
    gather_fused<true ><<<tile_blocks, 256, 0, stream>>>(roff, csrs, dinv, T2, bh + 0,   Wfh + 1 * 4096, T,  Nn);
    gather_fused<true ><<<tile_blocks, 256, 0, stream>>>(roff, csrs, dinv, T,  bh + 64,  Wfh + 2 * 4096, T2, Nn);
    gather_fused<true ><<<tile_blocks, 256, 0, stream>>>(roff, csrs, dinv, T2, bh + 128, Wfh + 3 * 4096, T,  Nn);
    gather_fused<false><<<tile_blocks, 256, 0, stream>>>(roff, csrs, dinv, T,  bh + 192, nullptr,        A,  Nn);

    // ---- global mean pool ----
    pool_graph<<<Gg, 256, 0, stream>>>(A, gstart, pooled);

    // ---- MLP head ----
    mlp1_kernel<<<(Gg * NHh + 255) / 256, 256, 0, stream>>>(pooled, W1, b1, hid);
    mlp2_kernel<<<(Gg * NOUTt + 255) / 256, 256, 0, stream>>>(hid, W2, b2, (float*)d_out);
}

// Round 15
// 359.308 us; speedup vs baseline: 1.2354x; 1.2354x over previous
//
#include <hip/hip_runtime.h>
#include <hip/hip_fp16.h>
#include <stddef.h>

static constexpr int Nn    = 100000;
static constexpr int Ee    = 1600000;
static constexpr int Ff    = 128;
static constexpr int Cc    = 64;
static constexpr int NHh   = 256;
static constexpr int NOUTt = 128;
static constexpr int Ll    = 4;
static constexpr int Gg    = 512;

static constexpr int SCAN_BLK = 1024;
static constexpr int NBLK_SCAN = (Nn + SCAN_BLK - 1) / SCAN_BLK;   // 98

static constexpr int NSUB   = (Nn + 511) / 512;   // 196
static constexpr int SUBCAP = 10240;

typedef _Float16 half8 __attribute__((ext_vector_type(8)));
typedef float    f32x4 __attribute__((ext_vector_type(4)));

// ---------------- pass 1: bin edges by dst>>9 into 196 sub-buckets ----------------
__global__ __launch_bounds__(256) void bin_kernel(const int* __restrict__ src,
                                                  const int* __restrict__ dst,
                                                  int* __restrict__ sb,
                                                  int* __restrict__ scnt, int E) {
    __shared__ int lcnt[NSUB], lbase[NSUB];
    const int tid = threadIdx.x;
    for (int i = tid; i < NSUB; i += 256) lcnt[i] = 0;
    __syncthreads();
    const int base = blockIdx.x * 2048;
    int pk[8], ps[8], lr[8];
    #pragma unroll
    for (int i = 0; i < 8; ++i) {
        int e = base + i * 256 + tid;
        if (e < E) {
            int d = dst[e], s = src[e];
            int sub = d >> 9;
            ps[i] = sub;
            pk[i] = s | ((d & 511) << 17);
            lr[i] = atomicAdd(&lcnt[sub], 1);
        } else ps[i] = -1;
    }
    __syncthreads();
    for (int i = tid; i < NSUB; i += 256) lbase[i] = atomicAdd(&scnt[i], lcnt[i]);
    __syncthreads();
    #pragma unroll
    for (int i = 0; i < 8; ++i) {
        if (ps[i] >= 0) {
            int pos = lbase[ps[i]] + lr[i];
            if (pos < SUBCAP) sb[(size_t)ps[i] * SUBCAP + pos] = pk[i];
        }
    }
}

// ---------------- pass 2a: degree + dinv ----------------
__global__ __launch_bounds__(512) void cnt3_kernel(const int* __restrict__ sb,
                                                   const int* __restrict__ scnt,
                                                   int* __restrict__ cnt,
                                                   float* __restrict__ dinv) {
    __shared__ int lcnt[512];
    const int sub = blockIdx.x, tid = threadIdx.x;
    lcnt[tid] = 0;
    __syncthreads();
    const int n = scnt[sub];
    const int* bp = sb + (size_t)sub * SUBCAP;
    for (int i = tid; i < n; i += 512) atomicAdd(&lcnt[(bp[i] >> 17) & 511], 1);
    __syncthreads();
    int node = sub * 512 + tid;
    if (node < Nn) {
        cnt[node] = lcnt[tid];
        dinv[node] = rsqrtf((float)lcnt[tid] + 1.0f);
    }
}

// ---------------- scans ----------------
__global__ __launch_bounds__(SCAN_BLK) void scan1_kernel(const int* __restrict__ cnt,
                                                         int* __restrict__ row_off,
                                                         int* __restrict__ bsum, int n) {
    __shared__ int sd[SCAN_BLK];
    int tid = threadIdx.x;
    int gid = blockIdx.x * SCAN_BLK + tid;
    int v = (gid < n) ? cnt[gid] : 0;
    sd[tid] = v;
    __syncthreads();
    #pragma unroll
    for (int off = 1; off < SCAN_BLK; off <<= 1) {
        int t = (tid >= off) ? sd[tid - off] : 0;
        __syncthreads();
        sd[tid] += t;
        __syncthreads();
    }
    if (gid < n) row_off[gid + 1] = sd[tid];
    if (tid == SCAN_BLK - 1) bsum[blockIdx.x] = sd[tid];
}

__global__ __launch_bounds__(128) void scan2_kernel(const int* __restrict__ bsum,
                                                    int* __restrict__ boff, int nb) {
    __shared__ int sd[128];
    int tid = threadIdx.x;
    sd[tid] = (tid < nb) ? bsum[tid] : 0;
    __syncthreads();
    #pragma unroll
    for (int off = 1; off < 128; off <<= 1) {
        int t = (tid >= off) ? sd[tid - off] : 0;
        __syncthreads();
        sd[tid] += t;
        __syncthreads();
    }
    if (tid < nb) boff[tid] = (tid == 0) ? 0 : sd[tid - 1];
}

__global__ void scan3_kernel(int* __restrict__ row_off, const int* __restrict__ boff,
                             const int* __restrict__ batch, int* __restrict__ gstart, int n) {
    int gid = blockIdx.x * blockDim.x + threadIdx.x;
    if (gid < n) {
        row_off[gid + 1] += boff[gid >> 10];
        int bi = batch[gid];
        int bp = (gid == 0) ? -1 : batch[gid - 1];
        for (int g = bp + 1; g <= bi; ++g) gstart[g] = gid;
        if (gid == n - 1) {
            for (int g = bi + 1; g <= Gg; ++g) gstart[g] = n;
        }
    }
    if (gid == 0) row_off[0] = 0;
}

// ---------------- pass 2b: fill csr ----------------
__global__ __launch_bounds__(512) void fill3_kernel(const int* __restrict__ sb,
                                                    const int* __restrict__ scnt,
                                                    const int* __restrict__ roff,
                                                    int* __restrict__ csr) {
    __shared__ int lcnt[512], lofs[512];
    __shared__ int gbase;
    const int sub = blockIdx.x, tid = threadIdx.x;
    lcnt[tid] = 0;
    if (tid == 0) gbase = roff[sub * 512];
    __syncthreads();
    const int n = scnt[sub];
    const int* bp = sb + (size_t)sub * SUBCAP;
    for (int i = tid; i < n; i += 512) atomicAdd(&lcnt[(bp[i] >> 17) & 511], 1);
    __syncthreads();
    int v = lcnt[tid];
    lofs[tid] = v;
    __syncthreads();
    #pragma unroll
    for (int off = 1; off < 512; off <<= 1) {
        int t = (tid >= off) ? lofs[tid - off] : 0;
        __syncthreads();
        lofs[tid] += t;
        __syncthreads();
    }
    int excl = lofs[tid] - v;
    __syncthreads();
    lcnt[tid] = excl;
    __syncthreads();
    for (int i = tid; i < n; i += 512) {
        int e = bp[i];
        int pos = atomicAdd(&lcnt[(e >> 17) & 511], 1);
        csr[gbase + pos] = e & 0x1FFFF;
    }
}

// ---------------- W pre-convert: W0 (128x64) + Wh (4x64x64) -> fragment-ordered fp16 ----
__global__ __launch_bounds__(512) void wcvt_kernel(const float* __restrict__ W0,
                                                   const float* __restrict__ Wh,
                                                   _Float16* __restrict__ Wf) {
    int t = blockIdx.x * blockDim.x + threadIdx.x;
    if (t < 1024) {
        int f = t >> 6, lane = t & 63;
        int ct = f >> 2, c = f & 3;
        _Float16* o = Wf + ((size_t)f * 64 + lane) * 8;
        int kbase = c * 32 + (lane >> 4) * 8;
        int col = ct * 16 + (lane & 15);
        #pragma unroll
        for (int j = 0; j < 8; ++j) o[j] = (_Float16)W0[(size_t)(kbase + j) * 64 + col];
    } else if (t < 1024 + 2048) {
        int u = t - 1024;
        int layer = u >> 9, rem = u & 511;
        int f = rem >> 6, lane = rem & 63;
        int ct = f >> 1, c = f & 1;
        _Float16* o = Wf + 8192 + (size_t)layer * 4096 + ((size_t)f * 64 + lane) * 8;
        int kbase = c * 32 + (lane >> 4) * 8;
        int col = ct * 16 + (lane & 15);
        #pragma unroll
        for (int j = 0; j < 8; ++j)
            o[j] = (_Float16)Wh[(size_t)layer * 4096 + (size_t)(kbase + j) * 64 + col];
    }
}

// ---------------- layer-0 GEMM via MFMA (K=128, in-register fp32->fp16) ----------------
__global__ __launch_bounds__(256) void gemm0_mfma(const float* __restrict__ X,
                                                  const _Float16* __restrict__ Wf0,
                                                  const float* __restrict__ dinv,
                                                  __half* __restrict__ Y, int n) {
    __shared__ _Float16 lds[4][16 * 72];
    const int tid = threadIdx.x, lane = tid & 63, w = tid >> 6;
    const int wid = (blockIdx.x * 256 + tid) >> 6;
    if (wid >= (n >> 4)) return;
    const int node0 = wid * 16;

    half8 bf[16];
    #pragma unroll
    for (int f = 0; f < 16; ++f)
        bf[f] = *(const half8*)(Wf0 + ((size_t)f * 64 + lane) * 8);

    const float* xp = X + (size_t)(node0 + (lane & 15)) * Ff + (lane >> 4) * 8;
    f32x4 acc[4] = {};
    #pragma unroll
    for (int c = 0; c < 4; ++c) {
        float4 x0 = *(const float4*)(xp + c * 32);
        float4 x1 = *(const float4*)(xp + c * 32 + 4);
        half8 af;
        af[0] = (_Float16)x0.x; af[1] = (_Float16)x0.y; af[2] = (_Float16)x0.z; af[3] = (_Float16)x0.w;
        af[4] = (_Float16)x1.x; af[5] = (_Float16)x1.y; af[6] = (_Float16)x1.z; af[7] = (_Float16)x1.w;
        #pragma unroll
        for (int ct = 0; ct < 4; ++ct)
            acc[ct] = __builtin_amdgcn_mfma_f32_16x16x32_f16(af, bf[ct * 4 + c], acc[ct], 0, 0, 0);
    }

    const int r0 = (lane >> 4) * 4;
    float di[4];
    #pragma unroll
    for (int r = 0; r < 4; ++r) di[r] = dinv[node0 + r0 + r];
    #pragma unroll
    for (int ct = 0; ct < 4; ++ct)
        #pragma unroll
        for (int r = 0; r < 4; ++r)
            lds[w][(r0 + r) * 72 + ct * 16 + (lane & 15)] = (_Float16)(acc[ct][r] * di[r]);
    asm volatile("s_waitcnt lgkmcnt(0)" ::: "memory");
    #pragma unroll
    for (int p = 0; p < 2; ++p) {
        int row = p * 8 + (lane >> 3);
        int ch  = lane & 7;
        half8 v = *(const half8*)&lds[w][row * 72 + ch * 8];
        *(half8*)((_Float16*)Y + (size_t)(node0 + row) * 64 + ch * 8) = v;
    }
}

// ---------------- hidden GEMM via MFMA: T = fp16( dinv * (H_f16 @ W) ) ----------------
__global__ __launch_bounds__(256) void gemm_mfma(const __half* __restrict__ A16,
                                                 const _Float16* __restrict__ Wf,
                                                 const float* __restrict__ dinv,
                                                 __half* __restrict__ Y, int n) {
    __shared__ _Float16 lds[4][16 * 72];
    const int tid  = threadIdx.x;
    const int lane = tid & 63;
    const int w    = tid >> 6;
    const int wid  = (blockIdx.x * 256 + tid) >> 6;
    if (wid >= (n >> 4)) return;
    const int node0 = wid * 16;

    half8 bfrag[8];
    #pragma unroll
    for (int f = 0; f < 8; ++f)
        bfrag[f] = *(const half8*)(Wf + ((size_t)f * 64 + lane) * 8);

    const _Float16* Ap = (const _Float16*)A16 + (size_t)(node0 + (lane & 15)) * 64 + (lane >> 4) * 8;
    half8 afrag0 = *(const half8*)(Ap);
    half8 afrag1 = *(const half8*)(Ap + 32);

    f32x4 acc[4] = {};
    #pragma unroll
    for (int ct = 0; ct < 4; ++ct) {
        acc[ct] = __builtin_amdgcn_mfma_f32_16x16x32_f16(afrag0, bfrag[ct * 2 + 0], acc[ct], 0, 0, 0);
        acc[ct] = __builtin_amdgcn_mfma_f32_16x16x32_f16(afrag1, bfrag[ct * 2 + 1], acc[ct], 0, 0, 0);
    }

    const int r0 = (lane >> 4) * 4;
    float di[4];
    #pragma unroll
    for (int r = 0; r < 4; ++r) di[r] = dinv[node0 + r0 + r];

    #pragma unroll
    for (int ct = 0; ct < 4; ++ct)
        #pragma unroll
        for (int r = 0; r < 4; ++r)
            lds[w][(r0 + r) * 72 + ct * 16 + (lane & 15)] = (_Float16)(acc[ct][r] * di[r]);

    asm volatile("s_waitcnt lgkmcnt(0)" ::: "memory");

    #pragma unroll
    for (int p = 0; p < 2; ++p) {
        int row = p * 8 + (lane >> 3);
        int ch  = lane & 7;
        half8 v = *(const half8*)&lds[w][row * 72 + ch * 8];
        *(half8*)((_Float16*)Y + (size_t)(node0 + row) * 64 + ch * 8) = v;
    }
}

// ---------------- fp16 helpers ----------------
__device__ inline void add_h8(float acc[8], float4 raw) {
    const __half2* hp = reinterpret_cast<const __half2*>(&raw);
    #pragma unroll
    for (int j = 0; j < 4; ++j) {
        float2 f = __half22float2(hp[j]);
        acc[2 * j]     += f.x;
        acc[2 * j + 1] += f.y;
    }
}

__device__ inline void cvt_h8(float4 raw, float v[8]) {
    const __half2* hp = reinterpret_cast<const __half2*>(&raw);
    #pragma unroll
    for (int j = 0; j < 4; ++j) {
        float2 f = __half22float2(hp[j]);
        v[2 * j] = f.x; v[2 * j + 1] = f.y;
    }
}

// ---------------- CSR gather-aggregate over fp16 t' -> fp16 h ----------------
// one wave per node (max TLP for latency hiding); 8 edge-slots of 8 lanes;
// up to 4 independent 16B loads in flight per lane.
__global__ __launch_bounds__(256) void gather_agg(const int* __restrict__ row_off,
                                                  const int* __restrict__ csr_src,
                                                  const float* __restrict__ dinv,
                                                  const __half* __restrict__ t,
                                                  const float* __restrict__ b,
                                                  __half* __restrict__ out, int n) {
    const int lane = threadIdx.x & 63;
    const int node = (blockIdx.x * blockDim.x + threadIdx.x) >> 6;
    if (node >= n) return;
    const int sub = lane >> 3;
    const int c8  = lane & 7;

    const int base = row_off[node];
    const int end  = row_off[node + 1];

    float acc[8] = {};

    for (int k0 = base; k0 < end; k0 += 64) {
        int myidx = (k0 + lane < end) ? csr_src[k0 + lane] : 0;
        int nk = min(64, end - k0);
        int k = 0;
        for (; k + 32 <= nk; k += 32) {
            int s0 = __shfl(myidx, k + sub);
            int s1 = __shfl(myidx, k + 8 + sub);
            int s2 = __shfl(myidx, k + 16 + sub);
            int s3 = __shfl(myidx, k + 24 + sub);
            float4 r0 = *(const float4*)(t + (size_t)s0 * 64 + c8 * 8);
            float4 r1 = *(const float4*)(t + (size_t)s1 * 64 + c8 * 8);
            float4 r2 = *(const float4*)(t + (size_t)s2 * 64 + c8 * 8);
            float4 r3 = *(const float4*)(t + (size_t)s3 * 64 + c8 * 8);
            add_h8(acc, r0);
            add_h8(acc, r1);
            add_h8(acc, r2);
            add_h8(acc, r3);
        }
        for (; k + 16 <= nk; k += 16) {
            int s0 = __shfl(myidx, k + sub);
            int s1 = __shfl(myidx, k + 8 + sub);
            float4 r0 = *(const float4*)(t + (size_t)s0 * 64 + c8 * 8);
            float4 r1 = *(const float4*)(t + (size_t)s1 * 64 + c8 * 8);
            add_h8(acc, r0);
            add_h8(acc, r1);
        }
        for (; k < nk; k += 8) {
            int kk = k + sub;
            int s = __shfl(myidx, kk);
            if (kk < nk) {
                float4 r = *(const float4*)(t + (size_t)s * 64 + c8 * 8);
                add_h8(acc, r);
            }
        }
    }

    #pragma unroll
    for (int off = 8; off < 64; off <<= 1) {
        #pragma unroll
        for (int j = 0; j < 8; ++j) acc[j] += __shfl_xor(acc[j], off);
    }

    if (sub == 0) {
        float di = dinv[node];
        float selfv[8];
        cvt_h8(*(const float4*)(t + (size_t)node * 64 + c8 * 8), selfv);
        float4 b0 = *(const float4*)(b + c8 * 8);
        float4 b1 = *(const float4*)(b + c8 * 8 + 4);
        float bb[8] = {b0.x, b0.y, b0.z, b0.w, b1.x, b1.y, b1.z, b1.w};
        __half2 o[4];
        #pragma unroll
        for (int j = 0; j < 4; ++j) {
            float v0 = fmaxf(di * (acc[2 * j]     + selfv[2 * j])     + bb[2 * j],     0.f);
            float v1 = fmaxf(di * (acc[2 * j + 1] + selfv[2 * j + 1]) + bb[2 * j + 1], 0.f);
            o[j] = __floats2half2_rn(v0, v1);
        }
        *(float4*)(out + (size_t)node * 64 + c8 * 8) = *reinterpret_cast<float4*>(o);
    }
}

// ---------------- pooling via sorted-batch segments ----------------
__global__ __launch_bounds__(256) void pool_graph(const __half* __restrict__ h,
                                                  const int* __restrict__ gstart,
                                                  float* __restrict__ pooled) {
    __shared__ float sd[4][64];
    const int g    = blockIdx.x;
    const int lane = threadIdx.x & 63;
    const int wv   = threadIdx.x >> 6;
    const int s = gstart[g], e = gstart[g + 1];
    float acc = 0.f;
    for (int i = s + wv; i < e; i += 4) acc += __half2float(h[(size_t)i * 64 + lane]);
    sd[wv][lane] = acc;
    __syncthreads();
    if (wv == 0) {
        float sum = sd[0][lane] + sd[1][lane] + sd[2][lane] + sd[3][lane];
        float c = (float)(e - s);
        pooled[(size_t)g * 64 + lane] = sum / fmaxf(c, 1.f);
    }
}

// ---------------- MLP head ----------------
__global__ void mlp1_kernel(const float* __restrict__ P, const float* __restrict__ W1,
                            const float* __restrict__ b1, float* __restrict__ H) {
    int gid = blockIdx.x * blockDim.x + threadIdx.x;
    if (gid >= Gg * NHh) return;
    int j = gid & (NHh - 1), g = gid >> 8;
    const float* p = P + (size_t)g * Cc;
    float s = b1[j];
    #pragma unroll 8
    for (int k = 0; k < Cc; ++k) s += p[k] * W1[(size_t)k * NHh + j];
    H[gid] = fmaxf(s, 0.f);
}

__global__ void mlp2_kernel(const float* __restrict__ H, const float* __restrict__ W2,
                            const float* __restrict__ b2, float* __restrict__ O) {
    int gid = blockIdx.x * blockDim.x + threadIdx.x;
    if (gid >= Gg * NOUTt) return;
    int j = gid & (NOUTt - 1), g = gid >> 7;
    const float* h = H + (size_t)g * NHh;
    float s = b2[j];
    #pragma unroll 8
    for (int k = 0; k < NHh; ++k) s += h[k] * W2[(size_t)k * NOUTt + j];
    O[gid] = s;
}

// ---------------- launch ----------------
extern "C" void kernel_launch(void* const* d_in, const int* in_sizes, int n_in,
                              void* d_out, int out_size, void* d_ws, size_t ws_size,
                              hipStream_t stream) {
    const float* x     = (const float*)d_in[0];
    const int*   ei    = (const int*)  d_in[1];
    const int*   batch = (const int*)  d_in[2];
    const float* W0    = (const float*)d_in[3];
    const float* b0    = (const float*)d_in[4];
    const float* Wh    = (const float*)d_in[5];
    const float* bh    = (const float*)d_in[6];
    const float* W1    = (const float*)d_in[7];
    const float* b1    = (const float*)d_in[8];
    const float* W2    = (const float*)d_in[9];
    const float* b2    = (const float*)d_in[10];

    const int* src = ei;
    const int* dst = ei + Ee;

    char* ws = (char*)d_ws;
    constexpr size_t OFF_DINV  = 0;
    constexpr size_t OFF_CNT   = 400384;
    constexpr size_t OFF_ROFF  = OFF_CNT + 400384;
    constexpr size_t OFF_BSUM  = OFF_ROFF + 400384;
    constexpr size_t OFF_BOFF  = OFF_BSUM + 1024;
    constexpr size_t OFF_SCNT  = OFF_BOFF + 1024;
    constexpr size_t OFF_CSR   = OFF_SCNT + 1024;
    constexpr size_t OFF_T     = OFF_CSR + 6400256;       // fp16 t' 12.8MB
    constexpr size_t OFF_A     = OFF_T + 12800256;        // fp16 h 12.8MB
    constexpr size_t OFF_POOL  = OFF_A + 12800256;
    constexpr size_t OFF_GST   = OFF_POOL + (size_t)Gg * Cc * 4;
    constexpr size_t OFF_HID   = OFF_GST + 4096;
    constexpr size_t OFF_WF    = OFF_HID + (size_t)Gg * NHh * 4;  // 48KB frag W0+Wh
    const size_t OFF_SB = OFF_T;   // sub-buckets (8.03MB) alias T (dead until gemm0)

    float*    dinv   = (float*)   (ws + OFF_DINV);
    int*      cnt    = (int*)     (ws + OFF_CNT);
    int*      roff   = (int*)     (ws + OFF_ROFF);
    int*      bsum   = (int*)     (ws + OFF_BSUM);
    int*      boff   = (int*)     (ws + OFF_BOFF);
    int*      scnt   = (int*)     (ws + OFF_SCNT);
    int*      csrs   = (int*)     (ws + OFF_CSR);
    int*      sb     = (int*)     (ws + OFF_SB);
    __half*   T      = (__half*)  (ws + OFF_T);
    __half*   A      = (__half*)  (ws + OFF_A);
    float*    pooled = (float*)   (ws + OFF_POOL);
    int*      gstart = (int*)     (ws + OFF_GST);
    float*    hid    = (float*)   (ws + OFF_HID);
    _Float16* Wf     = (_Float16*)(ws + OFF_WF);
    _Float16* Wfh    = Wf + 8192;

    // ---- CSR build + W pre-convert ----
    hipMemsetAsync(scnt, 0, 1024, stream);
    wcvt_kernel<<<6, 512, 0, stream>>>(W0, Wh, Wf);
    bin_kernel<<<(Ee + 2047) / 2048, 256, 0, stream>>>(src, dst, sb, scnt, Ee);
    cnt3_kernel<<<NSUB, 512, 0, stream>>>(sb, scnt, cnt, dinv);
    scan1_kernel<<<NBLK_SCAN, SCAN_BLK, 0, stream>>>(cnt, roff, bsum, Nn);
    scan2_kernel<<<1, 128, 0, stream>>>(bsum, boff, NBLK_SCAN);
    scan3_kernel<<<(Nn + 255) / 256, 256, 0, stream>>>(roff, boff, batch, gstart, Nn);
    fill3_kernel<<<NSUB, 512, 0, stream>>>(sb, scnt, roff, csrs);

    const int agg_blocks  = (Nn * 64 + 255) / 256;
    const int tile_blocks = ((Nn / 16) + 3) / 4;   // 1563

    // ---- layer 0: MFMA gemm (x fp32 -> T fp16) -> gather -> h(fp16) in A ----
    gemm0_mfma<<<tile_blocks, 256, 0, stream>>>(x, Wf, dinv, T, Nn);
    gather_agg<<<agg_blocks, 256, 0, stream>>>(roff, csrs, dinv, T, b0, A, Nn);

    // ---- hidden layers: MFMA gemm(A -> T), gather(T -> A) ----
    for (int i = 0; i < Ll; ++i) {
        gemm_mfma<<<tile_blocks, 256, 0, stream>>>(A, Wfh + (size_t)i * 4096, dinv, T, Nn);
        gather_agg<<<agg_blocks, 256, 0, stream>>>(roff, csrs, dinv, T, bh + (size_t)i * Cc, A, Nn);
    }

    // ---- global mean pool ----
    pool_graph<<<Gg, 256, 0, stream>>>(A, gstart, pooled);

    // ---- MLP head ----
    mlp1_kernel<<<(Gg * NHh + 255) / 256, 256, 0, stream>>>(pooled, W1, b1, hid);
    mlp2_kernel<<<(Gg * NOUTt + 255) / 256, 256, 0, stream>>>(hid, W2, b2, (float*)d_out);
}

// Round 17
// 350.115 us; speedup vs baseline: 1.2679x; 1.0263x over previous
//
#include <hip/hip_runtime.h>
#include <hip/hip_fp16.h>
#include <stddef.h>

static constexpr int Nn    = 100000;
static constexpr int Ee    = 1600000;
static constexpr int Ff    = 128;
static constexpr int Cc    = 64;
static constexpr int NHh   = 256;
static constexpr int NOUTt = 128;
static constexpr int Ll    = 4;
static constexpr int Gg    = 512;

// sub-bucket = 512 contiguous nodes (dst>>9); one block owns one sub-bucket's
// csr segment -> dirty lines flush once. Padded CSR: segment base = sub*SUBCAP,
// so no global prefix sum is needed (per-node start/end arrays instead).
static constexpr int NSUB   = (Nn + 511) / 512;   // 196
static constexpr int SUBCAP = 10240;              // mean 8163/bucket, +23 sigma

typedef _Float16 half8 __attribute__((ext_vector_type(8)));
typedef float    f32x4 __attribute__((ext_vector_type(4)));

// ---------------- pass 1: bin edges by dst>>9 into 196 sub-buckets ----------------
__global__ __launch_bounds__(256) void bin_kernel(const int* __restrict__ src,
                                                  const int* __restrict__ dst,
                                                  int* __restrict__ sb,
                                                  int* __restrict__ scnt, int E) {
    __shared__ int lcnt[NSUB], lbase[NSUB];
    const int tid = threadIdx.x;
    for (int i = tid; i < NSUB; i += 256) lcnt[i] = 0;
    __syncthreads();
    const int base = blockIdx.x * 2048;
    int pk[8], ps[8], lr[8];
    #pragma unroll
    for (int i = 0; i < 8; ++i) {
        int e = base + i * 256 + tid;
        if (e < E) {
            int d = dst[e], s = src[e];
            int sub = d >> 9;
            ps[i] = sub;
            pk[i] = s | ((d & 511) << 17);
            lr[i] = atomicAdd(&lcnt[sub], 1);
        } else ps[i] = -1;
    }
    __syncthreads();
    for (int i = tid; i < NSUB; i += 256) lbase[i] = atomicAdd(&scnt[i], lcnt[i]);
    __syncthreads();
    #pragma unroll
    for (int i = 0; i < 8; ++i) {
        if (ps[i] >= 0) {
            int pos = lbase[ps[i]] + lr[i];
            if (pos < SUBCAP) sb[(size_t)ps[i] * SUBCAP + pos] = pk[i];
        }
    }
}

// ---------------- pass 2: single-pass CSR build (count+scan+dinv+gbounds+fill) ----------------
__global__ __launch_bounds__(512) void fill_all(const int* __restrict__ sb,
                                                const int* __restrict__ scnt,
                                                const int* __restrict__ batch,
                                                int* __restrict__ rs,
                                                int* __restrict__ re,
                                                float* __restrict__ dinv,
                                                int* __restrict__ gstart,
                                                int* __restrict__ csr) {
    __shared__ int lcnt[512], lofs[512];
    const int sub = blockIdx.x, tid = threadIdx.x;
    lcnt[tid] = 0;
    __syncthreads();
    const int n = scnt[sub];
    const int* bp = sb + (size_t)sub * SUBCAP;
    for (int i = tid; i < n; i += 512) atomicAdd(&lcnt[(bp[i] >> 17) & 511], 1);
    __syncthreads();
    int v = lcnt[tid];
    lofs[tid] = v;
    __syncthreads();
    #pragma unroll
    for (int off = 1; off < 512; off <<= 1) {
        int t = (tid >= off) ? lofs[tid - off] : 0;
        __syncthreads();
        lofs[tid] += t;
        __syncthreads();
    }
    const int excl  = lofs[tid] - v;
    const int gbase = sub * SUBCAP;
    const int node  = sub * 512 + tid;
    if (node < Nn) {
        rs[node]   = gbase + excl;
        re[node]   = gbase + excl + v;
        dinv[node] = rsqrtf((float)v + 1.0f);   // + self loop
        int bi = batch[node];
        int bpv = (node == 0) ? -1 : batch[node - 1];
        for (int g = bpv + 1; g <= bi; ++g) gstart[g] = node;
        if (node == Nn - 1) {
            for (int g = bi + 1; g <= Gg; ++g) gstart[g] = Nn;
        }
    }
    __syncthreads();
    lcnt[tid] = excl;          // running cursor
    __syncthreads();
    for (int i = tid; i < n; i += 512) {
        int e = bp[i];
        int pos = atomicAdd(&lcnt[(e >> 17) & 511], 1);
        csr[gbase + pos] = e & 0x1FFFF;
    }
}

// ---------------- W pre-convert: W0 (128x64) + Wh (4x64x64) -> fragment-ordered fp16 ----
__global__ __launch_bounds__(512) void wcvt_kernel(const float* __restrict__ W0,
                                                   const float* __restrict__ Wh,
                                                   _Float16* __restrict__ Wf) {
    int t = blockIdx.x * blockDim.x + threadIdx.x;
    if (t < 1024) {
        int f = t >> 6, lane = t & 63;
        int ct = f >> 2, c = f & 3;
        _Float16* o = Wf + ((size_t)f * 64 + lane) * 8;
        int kbase = c * 32 + (lane >> 4) * 8;
        int col = ct * 16 + (lane & 15);
        #pragma unroll
        for (int j = 0; j < 8; ++j) o[j] = (_Float16)W0[(size_t)(kbase + j) * 64 + col];
    } else if (t < 1024 + 2048) {
        int u = t - 1024;
        int layer = u >> 9, rem = u & 511;
        int f = rem >> 6, lane = rem & 63;
        int ct = f >> 1, c = f & 1;
        _Float16* o = Wf + 8192 + (size_t)layer * 4096 + ((size_t)f * 64 + lane) * 8;
        int kbase = c * 32 + (lane >> 4) * 8;
        int col = ct * 16 + (lane & 15);
        #pragma unroll
        for (int j = 0; j < 8; ++j)
            o[j] = (_Float16)Wh[(size_t)layer * 4096 + (size_t)(kbase + j) * 64 + col];
    }
}

// ---------------- layer-0 GEMM via MFMA (K=128, in-register fp32->fp16) ----------------
__global__ __launch_bounds__(256) void gemm0_mfma(const float* __restrict__ X,
                                                  const _Float16* __restrict__ Wf0,
                                                  const float* __restrict__ dinv,
                                                  __half* __restrict__ Y, int n) {
    __shared__ _Float16 lds[4][16 * 72];
    const int tid = threadIdx.x, lane = tid & 63, w = tid >> 6;
    const int wid = (blockIdx.x * 256 + tid) >> 6;
    if (wid >= (n >> 4)) return;
    const int node0 = wid * 16;

    half8 bf[16];
    #pragma unroll
    for (int f = 0; f < 16; ++f)
        bf[f] = *(const half8*)(Wf0 + ((size_t)f * 64 + lane) * 8);

    const float* xp = X + (size_t)(node0 + (lane & 15)) * Ff + (lane >> 4) * 8;
    f32x4 acc[4] = {};
    #pragma unroll
    for (int c = 0; c < 4; ++c) {
        float4 x0 = *(const float4*)(xp + c * 32);
        float4 x1 = *(const float4*)(xp + c * 32 + 4);
        half8 af;
        af[0] = (_Float16)x0.x; af[1] = (_Float16)x0.y; af[2] = (_Float16)x0.z; af[3] = (_Float16)x0.w;
        af[4] = (_Float16)x1.x; af[5] = (_Float16)x1.y; af[6] = (_Float16)x1.z; af[7] = (_Float16)x1.w;
        #pragma unroll
        for (int ct = 0; ct < 4; ++ct)
            acc[ct] = __builtin_amdgcn_mfma_f32_16x16x32_f16(af, bf[ct * 4 + c], acc[ct], 0, 0, 0);
    }

    const int r0 = (lane >> 4) * 4;
    float di[4];
    #pragma unroll
    for (int r = 0; r < 4; ++r) di[r] = dinv[node0 + r0 + r];
    #pragma unroll
    for (int ct = 0; ct < 4; ++ct)
        #pragma unroll
        for (int r = 0; r < 4; ++r)
            lds[w][(r0 + r) * 72 + ct * 16 + (lane & 15)] = (_Float16)(acc[ct][r] * di[r]);
    asm volatile("s_waitcnt lgkmcnt(0)" ::: "memory");
    #pragma unroll
    for (int p = 0; p < 2; ++p) {
        int row = p * 8 + (lane >> 3);
        int ch  = lane & 7;
        half8 v = *(const half8*)&lds[w][row * 72 + ch * 8];
        *(half8*)((_Float16*)Y + (size_t)(node0 + row) * 64 + ch * 8) = v;
    }
}

// ---------------- hidden GEMM via MFMA: T = fp16( dinv * (H_f16 @ W) ) ----------------
__global__ __launch_bounds__(256) void gemm_mfma(const __half* __restrict__ A16,
                                                 const _Float16* __restrict__ Wf,
                                                 const float* __restrict__ dinv,
                                                 __half* __restrict__ Y, int n) {
    __shared__ _Float16 lds[4][16 * 72];
    const int tid  = threadIdx.x;
    const int lane = tid & 63;
    const int w    = tid >> 6;
    const int wid  = (blockIdx.x * 256 + tid) >> 6;
    if (wid >= (n >> 4)) return;
    const int node0 = wid * 16;

    half8 bfrag[8];
    #pragma unroll
    for (int f = 0; f < 8; ++f)
        bfrag[f] = *(const half8*)(Wf + ((size_t)f * 64 + lane) * 8);

    const _Float16* Ap = (const _Float16*)A16 + (size_t)(node0 + (lane & 15)) * 64 + (lane >> 4) * 8;
    half8 afrag0 = *(const half8*)(Ap);
    half8 afrag1 = *(const half8*)(Ap + 32);

    f32x4 acc[4] = {};
    #pragma unroll
    for (int ct = 0; ct < 4; ++ct) {
        acc[ct] = __builtin_amdgcn_mfma_f32_16x16x32_f16(afrag0, bfrag[ct * 2 + 0], acc[ct], 0, 0, 0);
        acc[ct] = __builtin_amdgcn_mfma_f32_16x16x32_f16(afrag1, bfrag[ct * 2 + 1], acc[ct], 0, 0, 0);
    }

    const int r0 = (lane >> 4) * 4;
    float di[4];
    #pragma unroll
    for (int r = 0; r < 4; ++r) di[r] = dinv[node0 + r0 + r];

    #pragma unroll
    for (int ct = 0; ct < 4; ++ct)
        #pragma unroll
        for (int r = 0; r < 4; ++r)
            lds[w][(r0 + r) * 72 + ct * 16 + (lane & 15)] = (_Float16)(acc[ct][r] * di[r]);

    asm volatile("s_waitcnt lgkmcnt(0)" ::: "memory");

    #pragma unroll
    for (int p = 0; p < 2; ++p) {
        int row = p * 8 + (lane >> 3);
        int ch  = lane & 7;
        half8 v = *(const half8*)&lds[w][row * 72 + ch * 8];
        *(half8*)((_Float16*)Y + (size_t)(node0 + row) * 64 + ch * 8) = v;
    }
}

// ---------------- fp16 helpers ----------------
__device__ inline void add_h8(float acc[8], float4 raw) {
    const __half2* hp = reinterpret_cast<const __half2*>(&raw);
    #pragma unroll
    for (int j = 0; j < 4; ++j) {
        float2 f = __half22float2(hp[j]);
        acc[2 * j]     += f.x;
        acc[2 * j + 1] += f.y;
    }
}

__device__ inline void cvt_h8(float4 raw, float v[8]) {
    const __half2* hp = reinterpret_cast<const __half2*>(&raw);
    #pragma unroll
    for (int j = 0; j < 4; ++j) {
        float2 f = __half22float2(hp[j]);
        v[2 * j] = f.x; v[2 * j + 1] = f.y;
    }
}

// ---------------- CSR gather-aggregate over fp16 t' -> fp16 h ----------------
// one wave per node (max TLP); 8 edge-slots of 8 lanes; 4 loads in flight/lane.
__global__ __launch_bounds__(256) void gather_agg2(const int* __restrict__ rs,
                                                   const int* __restrict__ re,
                                                   const int* __restrict__ csr_src,
                                                   const float* __restrict__ dinv,
                                                   const __half* __restrict__ t,
                                                   const float* __restrict__ b,
                                                   __half* __restrict__ out, int n) {
    const int lane = threadIdx.x & 63;
    const int node = (blockIdx.x * blockDim.x + threadIdx.x) >> 6;
    if (node >= n) return;
    const int sub = lane >> 3;
    const int c8  = lane & 7;

    const int base = rs[node];
    const int end  = re[node];

    float acc[8] = {};

    for (int k0 = base; k0 < end; k0 += 64) {
        int myidx = (k0 + lane < end) ? csr_src[k0 + lane] : 0;
        int nk = min(64, end - k0);
        int k = 0;
        for (; k + 32 <= nk; k += 32) {
            int s0 = __shfl(myidx, k + sub);
            int s1 = __shfl(myidx, k + 8 + sub);
            int s2 = __shfl(myidx, k + 16 + sub);
            int s3 = __shfl(myidx, k + 24 + sub);
            float4 r0 = *(const float4*)(t + (size_t)s0 * 64 + c8 * 8);
            float4 r1 = *(const float4*)(t + (size_t)s1 * 64 + c8 * 8);
            float4 r2 = *(const float4*)(t + (size_t)s2 * 64 + c8 * 8);
            float4 r3 = *(const float4*)(t + (size_t)s3 * 64 + c8 * 8);
            add_h8(acc, r0);
            add_h8(acc, r1);
            add_h8(acc, r2);
            add_h8(acc, r3);
        }
        for (; k + 16 <= nk; k += 16) {
            int s0 = __shfl(myidx, k + sub);
            int s1 = __shfl(myidx, k + 8 + sub);
            float4 r0 = *(const float4*)(t + (size_t)s0 * 64 + c8 * 8);
            float4 r1 = *(const float4*)(t + (size_t)s1 * 64 + c8 * 8);
            add_h8(acc, r0);
            add_h8(acc, r1);
        }
        for (; k < nk; k += 8) {
            int kk = k + sub;
            int s = __shfl(myidx, kk);
            if (kk < nk) {
                float4 r = *(const float4*)(t + (size_t)s * 64 + c8 * 8);
                add_h8(acc, r);
            }
        }
    }

    #pragma unroll
    for (int off = 8; off < 64; off <<= 1) {
        #pragma unroll
        for (int j = 0; j < 8; ++j) acc[j] += __shfl_xor(acc[j], off);
    }

    if (sub == 0) {
        float di = dinv[node];
        float selfv[8];
        cvt_h8(*(const float4*)(t + (size_t)node * 64 + c8 * 8), selfv);
        float4 b0 = *(const float4*)(b + c8 * 8);
        float4 b1 = *(const float4*)(b + c8 * 8 + 4);
        float bb[8] = {b0.x, b0.y, b0.z, b0.w, b1.x, b1.y, b1.z, b1.w};
        __half2 o[4];
        #pragma unroll
        for (int j = 0; j < 4; ++j) {
            float v0 = fmaxf(di * (acc[2 * j]     + selfv[2 * j])     + bb[2 * j],     0.f);
            float v1 = fmaxf(di * (acc[2 * j + 1] + selfv[2 * j + 1]) + bb[2 * j + 1], 0.f);
            o[j] = __floats2half2_rn(v0, v1);
        }
        *(float4*)(out + (size_t)node * 64 + c8 * 8) = *reinterpret_cast<float4*>(o);
    }
}

// ---------------- pooling via sorted-batch segments ----------------
__global__ __launch_bounds__(256) void pool_graph(const __half* __restrict__ h,
                                                  const int* __restrict__ gstart,
                                                  float* __restrict__ pooled) {
    __shared__ float sd[4][64];
    const int g    = blockIdx.x;
    const int lane = threadIdx.x & 63;
    const int wv   = threadIdx.x >> 6;
    const int s = gstart[g], e = gstart[g + 1];
    float acc = 0.f;
    for (int i = s + wv; i < e; i += 4) acc += __half2float(h[(size_t)i * 64 + lane]);
    sd[wv][lane] = acc;
    __syncthreads();
    if (wv == 0) {
        float sum = sd[0][lane] + sd[1][lane] + sd[2][lane] + sd[3][lane];
        float c = (float)(e - s);
        pooled[(size_t)g * 64 + lane] = sum / fmaxf(c, 1.f);
    }
}

// ---------------- MLP head ----------------
__global__ void mlp1_kernel(const float* __restrict__ P, const float* __restrict__ W1,
                            const float* __restrict__ b1, float* __restrict__ H) {
    int gid = blockIdx.x * blockDim.x + threadIdx.x;
    if (gid >= Gg * NHh) return;
    int j = gid & (NHh - 1), g = gid >> 8;
    const float* p = P + (size_t)g * Cc;
    float s = b1[j];
    #pragma unroll 8
    for (int k = 0; k < Cc; ++k) s += p[k] * W1[(size_t)k * NHh + j];
    H[gid] = fmaxf(s, 0.f);
}

__global__ void mlp2_kernel(const float* __restrict__ H, const float* __restrict__ W2,
                            const float* __restrict__ b2, float* __restrict__ O) {
    int gid = blockIdx.x * blockDim.x + threadIdx.x;
    if (gid >= Gg * NOUTt) return;
    int j = gid & (NOUTt - 1), g = gid >> 7;
    const float* h = H + (size_t)g * NHh;
    float s = b2[j];
    #pragma unroll 8
    for (int k = 0; k < NHh; ++k) s += h[k] * W2[(size_t)k * NOUTt + j];
    O[gid] = s;
}

// ---------------- launch ----------------
extern "C" void kernel_launch(void* const* d_in, const int* in_sizes, int n_in,
                              void* d_out, int out_size, void* d_ws, size_t ws_size,
                              hipStream_t stream) {
    const float* x     = (const float*)d_in[0];
    const int*   ei    = (const int*)  d_in[1];
    const int*   batch = (const int*)  d_in[2];
    const float* W0    = (const float*)d_in[3];
    const float* b0    = (const float*)d_in[4];
    const float* Wh    = (const float*)d_in[5];
    const float* bh    = (const float*)d_in[6];
    const float* W1    = (const float*)d_in[7];
    const float* b1    = (const float*)d_in[8];
    const float* W2    = (const float*)d_in[9];
    const float* b2    = (const float*)d_in[10];

    const int* src = ei;
    const int* dst = ei + Ee;

    char* ws = (char*)d_ws;
    constexpr size_t OFF_DINV = 0;
    constexpr size_t OFF_RS   = 400384;
    constexpr size_t OFF_RE   = OFF_RS + 400384;
    constexpr size_t OFF_SCNT = OFF_RE + 400384;
    constexpr size_t OFF_CSR  = OFF_SCNT + 1024;                   // NSUB*SUBCAP*4 = 8028160
    constexpr size_t OFF_T    = OFF_CSR + (size_t)NSUB * SUBCAP * 4;
    constexpr size_t OFF_A    = OFF_T + 12800256;
    constexpr size_t OFF_POOL = OFF_A + 12800256;
    constexpr size_t OFF_GST  = OFF_POOL + (size_t)Gg * Cc * 4;
    constexpr size_t OFF_HID  = OFF_GST + 4096;
    constexpr size_t OFF_WF   = OFF_HID + (size_t)Gg * NHh * 4;
    const size_t OFF_SB = OFF_T;   // sub-buckets (8.03MB) alias T (dead until gemm0)

    float*    dinv   = (float*)   (ws + OFF_DINV);
    int*      rs     = (int*)     (ws + OFF_RS);
    int*      re     = (int*)     (ws + OFF_RE);
    int*      scnt   = (int*)     (ws + OFF_SCNT);
    int*      csrs   = (int*)     (ws + OFF_CSR);
    int*      sb     = (int*)     (ws + OFF_SB);
    __half*   T      = (__half*)  (ws + OFF_T);
    __half*   A      = (__half*)  (ws + OFF_A);
    float*    pooled = (float*)   (ws + OFF_POOL);
    int*      gstart = (int*)     (ws + OFF_GST);
    float*    hid    = (float*)   (ws + OFF_HID);
    _Float16* Wf     = (_Float16*)(ws + OFF_WF);
    _Float16* Wfh    = Wf + 8192;

    // ---- CSR build (2 kernels) + W pre-convert ----
    (void)hipMemsetAsync(scnt, 0, 1024, stream);
    wcvt_kernel<<<6, 512, 0, stream>>>(W0, Wh, Wf);
    bin_kernel<<<(Ee + 2047) / 2048, 256, 0, stream>>>(src, dst, sb, scnt, Ee);
    fill_all<<<NSUB, 512, 0, stream>>>(sb, scnt, batch, rs, re, dinv, gstart, csrs);

    const int agg_blocks  = (Nn * 64 + 255) / 256;
    const int tile_blocks = ((Nn / 16) + 3) / 4;   // 1563

    // ---- layer 0: MFMA gemm (x fp32 -> T fp16) -> gather -> h(fp16) in A ----
    gemm0_mfma<<<tile_blocks, 256, 0, stream>>>(x, Wf, dinv, T, Nn);
    gather_agg2<<<agg_blocks, 256, 0, stream>>>(rs, re, csrs, dinv, T, b0, A, Nn);

    // ---- hidden layers: MFMA gemm(A -> T), gather(T -> A) ----
    for (int i = 0; i < Ll; ++i) {
        gemm_mfma<<<tile_blocks, 256, 0, stream>>>(A, Wfh + (size_t)i * 4096, dinv, T, Nn);
        gather_agg2<<<agg_blocks, 256, 0, stream>>>(rs, re, csrs, dinv, T, bh + (size_t)i * Cc, A, Nn);
    }

    // ---- global mean pool ----
    pool_graph<<<Gg, 256, 0, stream>>>(A, gstart, pooled);

    // ---- MLP head ----
    mlp1_kernel<<<(Gg * NHh + 255) / 256, 256, 0, stream>>>(pooled, W1, b1, hid);
    mlp2_kernel<<<(Gg * NOUTt + 255) / 256, 256, 0, stream>>>(hid, W2, b2, (float*)d_out);
}